// Round 2
// baseline (954.282 us; speedup 1.0000x reference)
//
#include <hip/hip_runtime.h>

// SpecAdaConv2d via split-bf16 MFMA implicit GEMM.
// out[b,co,p] = sum_{ci,k} (alpha[b,ci]*w[co,ci,k]) * x[b,ci,p+shift(k)] + bias[co]
// fp32 -> (hi,lo) bf16 split on both w and x; 3 products hi*hi + hi*lo_x + lo_w*hi.
//
// R2: move the alpha-mul + bf16 split OUT of the conv kernel into a one-shot
// bandwidth-bound prepack_x pass that writes a zero-border-padded, channel-last
// tensor xq[chunk][b][258][258][32 hi|32 lo] (bf16). Conv staging becomes a pure
// 16B/lane copy (no VALU, no masks), LDS rows are 128B with XOR slot-swizzle
// slot^(px&7) on BOTH write and read -> conflict-free (was 10.5M conflict cyc).
// LDS 43.5KB -> 3 blocks/CU; launch_bounds(512,6) keeps VGPR<=85 (6 waves/SIMD).
// Host falls back to the R1 all-in-one kernel if ws_size < 136.5 MB.

typedef __attribute__((ext_vector_type(8))) short short8;
typedef __attribute__((ext_vector_type(4))) float float4v;

#define BB 8
#define CI_N 64
#define CO_N 64
#define HH 256
#define WW 256
#define TW 32
#define TH 8
#define HALO_W 34
#define HALO_H 10
#define HALO_PX (HALO_W * HALO_H)   // 340

// padded channel-last split-x layout: xq[chunk][b][gy<258][gx<258][64us = 32hi|32lo]
#define GP 258
#define XROW_US (GP * 64)                  // 16512 ushorts per padded row
#define XB_US   ((size_t)GP * XROW_US)     // 4,260,096 us per (chunk,b) plane
#define NFRAG (2 * 9 * 2 * 4 * 64 * 8)     // 73728 packed weight bf16 elems
#define XQ_OFF_US ((size_t)NFRAG)          // xq starts right after weights
#define XQ_US   (16 * XB_US)               // 2 chunks * 8 batches
#define WS_NEED ((XQ_OFF_US + XQ_US) * 2)  // bytes

#define SX_US (HALO_PX * 64)               // 21760 us = 43520 B LDS

__device__ __forceinline__ unsigned f2bf(float v) {
    unsigned u = __float_as_uint(v);
    return (u + 0x7FFFu + ((u >> 16) & 1u)) >> 16;   // RNE to bf16
}

__global__ void prepack_w(const float* __restrict__ w, ushort* __restrict__ wp) {
    int idx = blockIdx.x * 256 + threadIdx.x;
    if (idx >= NFRAG) return;
    int j     = idx & 7;
    int lane  = (idx >> 3) & 63;
    int mt    = (idx >> 9) & 3;
    int plane = (idx >> 11) & 1;
    int rest  = idx >> 12;            // chunk*9 + k, 0..17
    int k     = rest % 9;
    int chunk = rest / 9;
    int co = mt * 16 + (lane & 15);
    int ci = chunk * 32 + (lane >> 4) * 8 + j;
    float v = w[(co * CI_N + ci) * 9 + k];
    unsigned hi = f2bf(v);
    float fhi = __uint_as_float(hi << 16);
    unsigned lo = f2bf(v - fhi);
    wp[idx] = (ushort)(plane ? lo : hi);
}

// zero the 1-px border of every (chunk,b) plane: 1028 border cells each.
__global__ void zero_border(ushort* __restrict__ xq) {
    int g = blockIdx.x * 256 + threadIdx.x;   // need 16448 cells * 8 slots = 131584
    if (g >= 131584) return;
    int slot = g & 7;
    int rest = g >> 3;          // 0..16447
    int c  = rest % 1028;
    int cb = rest / 1028;       // chunk*8 + b
    int gy, gx;
    if (c < 258)      { gy = 0;   gx = c; }
    else if (c < 516) { gy = 257; gx = c - 258; }
    else { int r = c - 516; gy = 1 + (r >> 1); gx = (r & 1) ? 257 : 0; }
    size_t us = (size_t)cb * XB_US + (size_t)gy * XROW_US + (size_t)gx * 64 + slot * 8;
    short8 z = {0, 0, 0, 0, 0, 0, 0, 0};
    *(short8*)(xq + us) = z;
}

// x (b,ci,y,x) fp32 -> xq channel-last bf16 hi/lo with alpha folded in.
__global__ __launch_bounds__(256) void prepack_x(
    const float* __restrict__ x, const float* __restrict__ alpha,
    ushort* __restrict__ xq)
{
    __shared__ float sxT[32][65];
    __shared__ float sa[64];
    const int t = threadIdx.x;
    const int b = blockIdx.x >> 8;
    const int y = blockIdx.x & 255;
    if (t < 64) sa[t] = alpha[b * CI_N + t];
    const float* xb = x + (size_t)b * CI_N * HH * WW + (size_t)y * WW;
    const int lx = t >> 2, plane = (t >> 1) & 1, jh = t & 1;
    __syncthreads();
#pragma unroll 1
    for (int tile = 0; tile < 8; ++tile) {
        const int xt = tile >> 1, chunk = tile & 1;
        // load 32 ci x 64 x (coalesced 256B rows)
#pragma unroll
        for (int it = 0; it < 8; ++it) {
            int cil = it * 4 + (t >> 6);
            int ci  = chunk * 32 + cil;
            int xx  = xt * 64 + (t & 63);
            sxT[cil][t & 63] = xb[(size_t)ci * (HH * WW) + xx] * sa[ci];
        }
        __syncthreads();
        // emit 16 ushorts of (plane) for x-col lx
        unsigned pk[8];
#pragma unroll
        for (int jj = 0; jj < 16; jj += 2) {
            float v0 = sxT[jh * 16 + jj][lx];
            float v1 = sxT[jh * 16 + jj + 1][lx];
            unsigned h0 = f2bf(v0), h1 = f2bf(v1);
            unsigned o0 = h0, o1 = h1;
            if (plane) {
                o0 = f2bf(v0 - __uint_as_float(h0 << 16));
                o1 = f2bf(v1 - __uint_as_float(h1 << 16));
            }
            pk[jj >> 1] = o0 | (o1 << 16);
        }
        size_t us = (size_t)(chunk * 8 + b) * XB_US + (size_t)(y + 1) * XROW_US
                  + (size_t)(xt * 64 + lx + 1) * 64 + plane * 32 + jh * 16;
        *(uint4*)(xq + us)     = make_uint4(pk[0], pk[1], pk[2], pk[3]);
        *(uint4*)(xq + us + 8) = make_uint4(pk[4], pk[5], pk[6], pk[7]);
        __syncthreads();
    }
}

__global__ __launch_bounds__(512, 6) void conv_mfma(
    const ushort* __restrict__ xq,    // prepacked split-x (d_ws)
    const ushort* __restrict__ wp,    // packed weights (d_ws)
    const float* __restrict__ bias,   // (COUT)
    float* __restrict__ out)          // (B, COUT, H, W)
{
    __shared__ __align__(16) ushort sx[SX_US];  // 43520 B

    const int tid    = threadIdx.x;
    const int lane   = tid & 63;
    const int w_id   = tid >> 6;        // wave 0..7
    const int n_lane = lane & 15;
    const int q      = lane >> 4;
    const int b      = blockIdx.z;
    const int gx0    = blockIdx.x * TW;
    const int gy0    = blockIdx.y * TH;
    const int m_half = w_id >> 2;       // owns M-tiles m_half*2 + {0,1}
    const int n_q    = w_id & 3;        // owns N-tiles n_q*4 + {0..3}

    // acc init = bias (C/D layout: col=lane&15 -> px, row=q*4+r -> co)
    float4v acc[2][4];
#pragma unroll
    for (int mt = 0; mt < 2; ++mt) {
        float4v bi;
#pragma unroll
        for (int r = 0; r < 4; ++r)
            bi[r] = bias[(m_half * 2 + mt) * 16 + q * 4 + r];
#pragma unroll
        for (int nt = 0; nt < 4; ++nt) acc[mt][nt] = bi;
    }

    for (int chunk = 0; chunk < 2; ++chunk) {
        if (chunk) __syncthreads();   // LDS reuse fence

        // ---- stage: pure 16B/lane copy, XOR slot-swizzled LDS write ----
        short8 stg[6];
        int    lofs[6];
#pragma unroll
        for (int it = 0; it < 6; ++it) {
            int li = it * 512 + tid;            // 16B unit index, 2720 total
            if (li < SX_US / 8) {
                int px = li >> 3;               // halo pixel 0..339
                int sl = li & 7;                // 16B slot within 128B row
                int hy = px / HALO_W;
                int hx = px - hy * HALO_W;
                size_t g = (size_t)(chunk * 8 + b) * XB_US
                         + (size_t)(gy0 + hy) * XROW_US
                         + (size_t)(gx0 + hx) * 64 + sl * 8;
                stg[it]  = *(const short8*)(xq + g);
                lofs[it] = px * 64 + ((sl ^ (px & 7)) << 3);
            }
        }
#pragma unroll
        for (int it = 0; it < 6; ++it) {
            int li = it * 512 + tid;
            if (li < SX_US / 8) *(short8*)&sx[lofs[it]] = stg[it];
        }
        __syncthreads();

        // ---- compute: 9 shifts x (hi*hi, lo_w*hi, hi*lo_x) over K=32 ci ----
#pragma unroll
        for (int k = 0; k < 9; ++k) {
            const int dy = k / 3 - 1;
            const int dx = k % 3 - 1;
            // A-frags: coalesced dwordx4 from packed layout (L2-resident)
            short8 a_hi[2], a_lo[2];
#pragma unroll
            for (int mt = 0; mt < 2; ++mt) {
                int fh = ((chunk * 9 + k) * 2 + 0) * 4 + (m_half * 2 + mt);
                int fl = ((chunk * 9 + k) * 2 + 1) * 4 + (m_half * 2 + mt);
                a_hi[mt] = *(const short8*)(wp + (size_t)(fh * 64 + lane) * 8);
                a_lo[mt] = *(const short8*)(wp + (size_t)(fl * 64 + lane) * 8);
            }
#pragma unroll
            for (int nt_i = 0; nt_i < 4; ++nt_i) {
                const int prow = n_q * 2 + (nt_i >> 1) + 1 + dy;
                const int px   = prow * HALO_W + (nt_i & 1) * 16 + 1 + dx + n_lane;
                const int sw   = (q ^ (px & 7)) << 3;
                short8 b_hi = *(const short8*)&sx[px * 64 + sw];
                short8 b_lo = *(const short8*)&sx[px * 64 + (sw ^ 32)];
                acc[0][nt_i] = __builtin_amdgcn_mfma_f32_16x16x32_bf16(a_hi[0], b_hi, acc[0][nt_i], 0, 0, 0);
                acc[1][nt_i] = __builtin_amdgcn_mfma_f32_16x16x32_bf16(a_hi[1], b_hi, acc[1][nt_i], 0, 0, 0);
                acc[0][nt_i] = __builtin_amdgcn_mfma_f32_16x16x32_bf16(a_lo[0], b_hi, acc[0][nt_i], 0, 0, 0);
                acc[1][nt_i] = __builtin_amdgcn_mfma_f32_16x16x32_bf16(a_lo[1], b_hi, acc[1][nt_i], 0, 0, 0);
                acc[0][nt_i] = __builtin_amdgcn_mfma_f32_16x16x32_bf16(a_hi[0], b_lo, acc[0][nt_i], 0, 0, 0);
                acc[1][nt_i] = __builtin_amdgcn_mfma_f32_16x16x32_bf16(a_hi[1], b_lo, acc[1][nt_i], 0, 0, 0);
            }
        }
    }

    // ---- epilogue: store (64B-segment coalescing: 16 px x 4 co groups) ----
#pragma unroll
    for (int mt = 0; mt < 2; ++mt) {
        const int m0 = (m_half * 2 + mt) * 16;
#pragma unroll
        for (int nt_i = 0; nt_i < 4; ++nt_i) {
            const int nt = n_q * 4 + nt_i;
            const int gy = gy0 + (nt >> 1);
            const int gx = gx0 + (nt & 1) * 16 + n_lane;
#pragma unroll
            for (int r = 0; r < 4; ++r) {
                const int co = m0 + q * 4 + r;
                out[(((size_t)b * CO_N + co) * HH + gy) * WW + gx] = acc[mt][nt_i][r];
            }
        }
    }
}

// ---------------- fallback (R1 kernel, used if ws too small) ----------------
#define RS_FB 72
#define HI_OFF_FB 32

__global__ __launch_bounds__(512, 4) void conv_mfma_fb(
    const float* __restrict__ x, const float* __restrict__ alpha,
    const ushort* __restrict__ wp, const float* __restrict__ bias,
    float* __restrict__ out)
{
    __shared__ __align__(16) ushort sx[HALO_PX * RS_FB];

    const int tid    = threadIdx.x;
    const int lane   = tid & 63;
    const int w_id   = tid >> 6;
    const int n_lane = lane & 15;
    const int q      = lane >> 4;
    const int b      = blockIdx.z;
    const int gx0    = blockIdx.x * TW;
    const int gy0    = blockIdx.y * TH;
    const int m_half = w_id >> 2;
    const int n_q    = w_id & 3;

    float4v acc[2][4];
#pragma unroll
    for (int mt = 0; mt < 2; ++mt) {
        float4v bi;
#pragma unroll
        for (int r = 0; r < 4; ++r)
            bi[r] = bias[(m_half * 2 + mt) * 16 + q * 4 + r];
#pragma unroll
        for (int nt = 0; nt < 4; ++nt) acc[mt][nt] = bi;
    }

    const float* xb = x + (size_t)b * CI_N * HH * WW;
    const int vbase = (n_q * 2 * HALO_W + n_lane) * RS_FB + q * 8;

    for (int chunk = 0; chunk < 2; ++chunk) {
        if (chunk) __syncthreads();
#pragma unroll
        for (int p = 0; p < 2; ++p) {
            const int cl = w_id * 4 + p * 2;
            const int ci = chunk * 32 + cl;
            const float a0 = alpha[b * CI_N + ci];
            const float a1 = alpha[b * CI_N + ci + 1];
            const float* xp0 = xb + (size_t)ci * HH * WW;
            const float* xp1 = xp0 + HH * WW;
#pragma unroll
            for (int it = 0; it < 6; ++it) {
                int hp = it * 64 + lane;
                if (hp < HALO_PX) {
                    int hy = hp / HALO_W;
                    int hx = hp - hy * HALO_W;
                    int gy = gy0 - 1 + hy;
                    int gx = gx0 - 1 + hx;
                    bool ok = ((unsigned)gy < HH) & ((unsigned)gx < WW);
                    int gidx = gy * WW + gx;
                    float v0 = ok ? xp0[gidx] * a0 : 0.0f;
                    float v1 = ok ? xp1[gidx] * a1 : 0.0f;
                    unsigned h0 = f2bf(v0);
                    unsigned h1 = f2bf(v1);
                    float f0 = __uint_as_float(h0 << 16);
                    float f1 = __uint_as_float(h1 << 16);
                    unsigned l0 = f2bf(v0 - f0);
                    unsigned l1 = f2bf(v1 - f1);
                    *(unsigned*)&sx[hp * RS_FB + cl]             = h0 | (h1 << 16);
                    *(unsigned*)&sx[hp * RS_FB + HI_OFF_FB + cl] = l0 | (l1 << 16);
                }
            }
        }
        __syncthreads();
#pragma unroll
        for (int k = 0; k < 9; ++k) {
            const int dy = k / 3 - 1;
            const int dx = k % 3 - 1;
            short8 a_hi[2], a_lo[2];
#pragma unroll
            for (int mt = 0; mt < 2; ++mt) {
                int fh = ((chunk * 9 + k) * 2 + 0) * 4 + (m_half * 2 + mt);
                int fl = ((chunk * 9 + k) * 2 + 1) * 4 + (m_half * 2 + mt);
                a_hi[mt] = *(const short8*)(wp + (size_t)(fh * 64 + lane) * 8);
                a_lo[mt] = *(const short8*)(wp + (size_t)(fl * 64 + lane) * 8);
            }
#pragma unroll
            for (int nt_i = 0; nt_i < 4; ++nt_i) {
                const int off = ((nt_i >> 1) + 1 + dy) * HALO_W + 1 + (nt_i & 1) * 16 + dx;
                const ushort* bp = &sx[vbase + off * RS_FB];
                short8 b_hi = *(const short8*)bp;
                short8 b_lo = *(const short8*)(bp + HI_OFF_FB);
                acc[0][nt_i] = __builtin_amdgcn_mfma_f32_16x16x32_bf16(a_hi[0], b_hi, acc[0][nt_i], 0, 0, 0);
                acc[1][nt_i] = __builtin_amdgcn_mfma_f32_16x16x32_bf16(a_hi[1], b_hi, acc[1][nt_i], 0, 0, 0);
                acc[0][nt_i] = __builtin_amdgcn_mfma_f32_16x16x32_bf16(a_lo[0], b_hi, acc[0][nt_i], 0, 0, 0);
                acc[1][nt_i] = __builtin_amdgcn_mfma_f32_16x16x32_bf16(a_lo[1], b_hi, acc[1][nt_i], 0, 0, 0);
                acc[0][nt_i] = __builtin_amdgcn_mfma_f32_16x16x32_bf16(a_hi[0], b_lo, acc[0][nt_i], 0, 0, 0);
                acc[1][nt_i] = __builtin_amdgcn_mfma_f32_16x16x32_bf16(a_hi[1], b_lo, acc[1][nt_i], 0, 0, 0);
            }
        }
    }

#pragma unroll
    for (int mt = 0; mt < 2; ++mt) {
        const int m0 = (m_half * 2 + mt) * 16;
#pragma unroll
        for (int nt_i = 0; nt_i < 4; ++nt_i) {
            const int nt = n_q * 4 + nt_i;
            const int gy = gy0 + (nt >> 1);
            const int gx = gx0 + (nt & 1) * 16 + n_lane;
#pragma unroll
            for (int r = 0; r < 4; ++r) {
                const int co = m0 + q * 4 + r;
                out[(((size_t)b * CO_N + co) * HH + gy) * WW + gx] = acc[mt][nt_i][r];
            }
        }
    }
}

extern "C" void kernel_launch(void* const* d_in, const int* in_sizes, int n_in,
                              void* d_out, int out_size, void* d_ws, size_t ws_size,
                              hipStream_t stream) {
    const float* x     = (const float*)d_in[0];
    const float* alpha = (const float*)d_in[1];
    const float* w     = (const float*)d_in[2];
    const float* bias  = (const float*)d_in[3];
    float* out  = (float*)d_out;
    ushort* wpk = (ushort*)d_ws;

    prepack_w<<<dim3((NFRAG + 255) / 256), dim3(256), 0, stream>>>(w, wpk);
    dim3 grid(WW / TW, HH / TH, BB);   // (8, 32, 8) = 2048 blocks

    if (ws_size >= WS_NEED) {
        ushort* xq = wpk + XQ_OFF_US;
        zero_border<<<dim3(514), dim3(256), 0, stream>>>(xq);
        prepack_x<<<dim3(BB * HH), dim3(256), 0, stream>>>(x, alpha, xq);
        conv_mfma<<<grid, dim3(512), 0, stream>>>(xq, wpk, bias, out);
    } else {
        conv_mfma_fb<<<grid, dim3(512), 0, stream>>>(x, alpha, wpk, bias, out);
    }
}

// Round 3
// 409.331 us; speedup vs baseline: 2.3313x; 2.3313x over previous
//
#include <hip/hip_runtime.h>

// SpecAdaConv2d via split-bf16 MFMA implicit GEMM.
// out[b,co,p] = sum_{ci,k} (alpha[b,ci]*w[co,ci,k]) * x[b,ci,p+shift(k)] + bias[co]
// fp32 -> (hi,lo) bf16 split on both w and x; 3 products hi*hi + hi*lo_x + lo_w*hi.
//
// R3: revert R2's prepack_x (its launch_bounds(512,6) caused scratch spills:
// VGPR 40 + 1.6GB scratch writes -> 718us). Keep R2's verified swizzled LDS
// layout (128B rows [32 hi|32 lo], slot ^ (px&7), 43.5KB, 0 bank conflicts),
// stage inline from fp32 x: each lane owns one (px, 8-ci slot) unit ->
// 8 coalesced 4B loads, convert in-reg, two ds_write_b128 (conflict-free;
// R1's dword staging writes were 4-way conflicted = 10.5M cycles).
// launch_bounds(512,4) = proven no-spill. LDS caps occupancy at 3 blocks/CU.

typedef __attribute__((ext_vector_type(8))) short short8;
typedef __attribute__((ext_vector_type(4))) float float4v;

#define BB 8
#define CI_N 64
#define CO_N 64
#define HH 256
#define WW 256
#define TW 32
#define TH 8
#define HALO_W 34
#define HALO_H 10
#define HALO_PX (HALO_W * HALO_H)   // 340

#define NFRAG (2 * 9 * 2 * 4 * 64 * 8)  // 73728 packed weight bf16 elems
#define SX_US (HALO_PX * 64)            // 21760 ushorts = 43520 B LDS

__device__ __forceinline__ unsigned f2bf(float v) {
    unsigned u = __float_as_uint(v);
    return (u + 0x7FFFu + ((u >> 16) & 1u)) >> 16;   // RNE to bf16
}

__global__ void prepack_w(const float* __restrict__ w, ushort* __restrict__ wp) {
    int idx = blockIdx.x * 256 + threadIdx.x;
    if (idx >= NFRAG) return;
    int j     = idx & 7;
    int lane  = (idx >> 3) & 63;
    int mt    = (idx >> 9) & 3;
    int plane = (idx >> 11) & 1;
    int rest  = idx >> 12;            // chunk*9 + k, 0..17
    int k     = rest % 9;
    int chunk = rest / 9;
    int co = mt * 16 + (lane & 15);
    int ci = chunk * 32 + (lane >> 4) * 8 + j;
    float v = w[(co * CI_N + ci) * 9 + k];
    unsigned hi = f2bf(v);
    float fhi = __uint_as_float(hi << 16);
    unsigned lo = f2bf(v - fhi);
    wp[idx] = (ushort)(plane ? lo : hi);
}

__global__ __launch_bounds__(512, 4) void conv_mfma(
    const float* __restrict__ x,      // (B, CIN, H, W)
    const float* __restrict__ alpha,  // (B, CIN)
    const ushort* __restrict__ wp,    // packed weights (d_ws)
    const float* __restrict__ bias,   // (COUT)
    float* __restrict__ out)          // (B, COUT, H, W)
{
    __shared__ __align__(16) ushort sx[SX_US];  // 43520 B

    const int tid    = threadIdx.x;
    const int lane   = tid & 63;
    const int w_id   = tid >> 6;        // wave 0..7
    const int n_lane = lane & 15;
    const int q      = lane >> 4;
    const int b      = blockIdx.z;
    const int gx0    = blockIdx.x * TW;
    const int gy0    = blockIdx.y * TH;
    const int m_half = w_id >> 2;       // owns M-tiles m_half*2 + {0,1}
    const int n_q    = w_id & 3;        // owns N-tiles n_q*4 + {0..3}

    // acc init = bias (C/D layout: col=lane&15 -> px, row=q*4+r -> co)
    float4v acc[2][4];
#pragma unroll
    for (int mt = 0; mt < 2; ++mt) {
        float4v bi;
#pragma unroll
        for (int r = 0; r < 4; ++r)
            bi[r] = bias[(m_half * 2 + mt) * 16 + q * 4 + r];
#pragma unroll
        for (int nt = 0; nt < 4; ++nt) acc[mt][nt] = bi;
    }

    const float* xb = x + (size_t)b * CI_N * HH * WW;

    for (int chunk = 0; chunk < 2; ++chunk) {
        if (chunk) __syncthreads();   // LDS reuse fence

        // ---- stage: unit = (px, 8-ci slot). 8 coalesced loads, convert,
        //      two conflict-free ds_write_b128 at swizzled slots.        ----
#pragma unroll
        for (int it = 0; it < 3; ++it) {
            const int g  = it * 8 + w_id;       // 0..23
            const int s  = g / 6;               // slot group 0..3 (8 ci each)
            const int gi = g - s * 6;           // 0..5
            const int px = gi * 64 + lane;      // 0..383
            if (px < HALO_PX) {
                const int hy = px / HALO_W;
                const int hx = px - hy * HALO_W;
                const int gy = gy0 - 1 + hy;
                const int gx = gx0 - 1 + hx;
                const bool ok = ((unsigned)gy < HH) & ((unsigned)gx < WW);
                const int gofs = ok ? gy * WW + gx : 0;   // clamped: always valid
                const int ci0 = chunk * 32 + s * 8;
                const float* xp = xb + (size_t)ci0 * (HH * WW) + gofs;
                float v[8];
#pragma unroll
                for (int c = 0; c < 8; ++c) {
                    float t = xp[c * (HH * WW)] * alpha[b * CI_N + ci0 + c];
                    v[c] = ok ? t : 0.0f;
                }
                unsigned ph[4], pl[4];
#pragma unroll
                for (int j = 0; j < 4; ++j) {
                    unsigned h0 = f2bf(v[2 * j]);
                    unsigned h1 = f2bf(v[2 * j + 1]);
                    unsigned l0 = f2bf(v[2 * j]     - __uint_as_float(h0 << 16));
                    unsigned l1 = f2bf(v[2 * j + 1] - __uint_as_float(h1 << 16));
                    ph[j] = h0 | (h1 << 16);
                    pl[j] = l0 | (l1 << 16);
                }
                const int off = px * 64 + ((s ^ (px & 7)) << 3);
                *(uint4*)&sx[off]      = make_uint4(ph[0], ph[1], ph[2], ph[3]);
                *(uint4*)&sx[off ^ 32] = make_uint4(pl[0], pl[1], pl[2], pl[3]);
            }
        }
        __syncthreads();

        // ---- compute: 9 shifts x (hi*hi, lo_w*hi, hi*lo_x) over K=32 ci ----
#pragma unroll
        for (int k = 0; k < 9; ++k) {
            const int dy = k / 3 - 1;
            const int dx = k % 3 - 1;
            // A-frags: coalesced dwordx4 from packed layout (L2-resident)
            short8 a_hi[2], a_lo[2];
#pragma unroll
            for (int mt = 0; mt < 2; ++mt) {
                int fh = ((chunk * 9 + k) * 2 + 0) * 4 + (m_half * 2 + mt);
                int fl = ((chunk * 9 + k) * 2 + 1) * 4 + (m_half * 2 + mt);
                a_hi[mt] = *(const short8*)(wp + (size_t)(fh * 64 + lane) * 8);
                a_lo[mt] = *(const short8*)(wp + (size_t)(fl * 64 + lane) * 8);
            }
#pragma unroll
            for (int nt_i = 0; nt_i < 4; ++nt_i) {
                const int prow = n_q * 2 + (nt_i >> 1) + 1 + dy;
                const int px   = prow * HALO_W + (nt_i & 1) * 16 + 1 + dx + n_lane;
                const int sw   = (q ^ (px & 7)) << 3;
                short8 b_hi = *(const short8*)&sx[px * 64 + sw];
                short8 b_lo = *(const short8*)&sx[px * 64 + (sw ^ 32)];
                acc[0][nt_i] = __builtin_amdgcn_mfma_f32_16x16x32_bf16(a_hi[0], b_hi, acc[0][nt_i], 0, 0, 0);
                acc[1][nt_i] = __builtin_amdgcn_mfma_f32_16x16x32_bf16(a_hi[1], b_hi, acc[1][nt_i], 0, 0, 0);
                acc[0][nt_i] = __builtin_amdgcn_mfma_f32_16x16x32_bf16(a_lo[0], b_hi, acc[0][nt_i], 0, 0, 0);
                acc[1][nt_i] = __builtin_amdgcn_mfma_f32_16x16x32_bf16(a_lo[1], b_hi, acc[1][nt_i], 0, 0, 0);
                acc[0][nt_i] = __builtin_amdgcn_mfma_f32_16x16x32_bf16(a_hi[0], b_lo, acc[0][nt_i], 0, 0, 0);
                acc[1][nt_i] = __builtin_amdgcn_mfma_f32_16x16x32_bf16(a_hi[1], b_lo, acc[1][nt_i], 0, 0, 0);
            }
        }
    }

    // ---- epilogue: store (64B-segment coalescing: 16 px x 4 co groups) ----
#pragma unroll
    for (int mt = 0; mt < 2; ++mt) {
        const int m0 = (m_half * 2 + mt) * 16;
#pragma unroll
        for (int nt_i = 0; nt_i < 4; ++nt_i) {
            const int nt = n_q * 4 + nt_i;
            const int gy = gy0 + (nt >> 1);
            const int gx = gx0 + (nt & 1) * 16 + n_lane;
#pragma unroll
            for (int r = 0; r < 4; ++r) {
                const int co = m0 + q * 4 + r;
                out[(((size_t)b * CO_N + co) * HH + gy) * WW + gx] = acc[mt][nt_i][r];
            }
        }
    }
}

extern "C" void kernel_launch(void* const* d_in, const int* in_sizes, int n_in,
                              void* d_out, int out_size, void* d_ws, size_t ws_size,
                              hipStream_t stream) {
    const float* x     = (const float*)d_in[0];
    const float* alpha = (const float*)d_in[1];
    const float* w     = (const float*)d_in[2];
    const float* bias  = (const float*)d_in[3];
    float* out  = (float*)d_out;
    ushort* wpk = (ushort*)d_ws;

    prepack_w<<<dim3((NFRAG + 255) / 256), dim3(256), 0, stream>>>(w, wpk);

    dim3 grid(WW / TW, HH / TH, BB);   // (8, 32, 8) = 2048 blocks
    conv_mfma<<<grid, dim3(512), 0, stream>>>(x, alpha, wpk, bias, out);
}

// Round 4
// 378.901 us; speedup vs baseline: 2.5186x; 1.0803x over previous
//
#include <hip/hip_runtime.h>

// SpecAdaConv2d via split-bf16 MFMA implicit GEMM.
// out[b,co,p] = sum_{ci,k} (alpha[b,ci]*w[co,ci,k]) * x[b,ci,p+shift(k)] + bias[co]
// fp32 -> (hi,lo) bf16 split on both w and x; 3 products hi*hi + hi*lo_x + lo_w*hi.
//
// R4 = R1 structure (proven 218us conv: streaming 2-plane staging, RS=72 LDS,
// VGPR=64 which sits exactly on the m69 occupancy quantum) + XCD-aware block
// swizzle. Old grid (8,32,8): XCD = linear%8 = tile-x -> x-neighbor tiles never
// share an L2; each XCD touches all 8 images. New 1-D grid: b = id&7 (XCD k
// owns batch k, 16.8MB), tiles row-major within XCD -> halo re-reads (1.66x
// redundancy) become L2 hits. R3's conflict-free staging REVERTED: measured
// A/B showed its strided 8-plane loads cost +40us and +176MB HBM while the
// write conflicts it removed were latency-hidden (free).

typedef __attribute__((ext_vector_type(8))) short short8;
typedef __attribute__((ext_vector_type(4))) float float4v;

#define BB 8
#define CI_N 64
#define CO_N 64
#define HH 256
#define WW 256
#define TW 32
#define TH 8
#define HALO_W 34
#define HALO_H 10
#define HALO_PX (HALO_W * HALO_H)   // 340
#define RS 72                        // packed row: [32 hi][32 lo][8 pad] ushorts
#define HI_OFF 32                    // lo block starts 32 ushorts (64 B) into row

#define NFRAG (2 * 9 * 2 * 4 * 64 * 8)  // 73728 packed bf16 elems

__device__ __forceinline__ unsigned f2bf(float v) {
    unsigned u = __float_as_uint(v);
    return (u + 0x7FFFu + ((u >> 16) & 1u)) >> 16;   // RNE to bf16
}

__global__ void prepack_w(const float* __restrict__ w, ushort* __restrict__ wp) {
    int idx = blockIdx.x * 256 + threadIdx.x;
    if (idx >= NFRAG) return;
    int j     = idx & 7;
    int lane  = (idx >> 3) & 63;
    int mt    = (idx >> 9) & 3;
    int plane = (idx >> 11) & 1;
    int rest  = idx >> 12;            // chunk*9 + k, 0..17
    int k     = rest % 9;
    int chunk = rest / 9;
    int co = mt * 16 + (lane & 15);
    int ci = chunk * 32 + (lane >> 4) * 8 + j;
    float v = w[(co * CI_N + ci) * 9 + k];
    unsigned hi = f2bf(v);
    float fhi = __uint_as_float(hi << 16);
    unsigned lo = f2bf(v - fhi);
    wp[idx] = (ushort)(plane ? lo : hi);
}

__global__ __launch_bounds__(512, 4) void conv_mfma(
    const float* __restrict__ x,      // (B, CIN, H, W)
    const float* __restrict__ alpha,  // (B, CIN)
    const ushort* __restrict__ wp,    // packed weights (d_ws)
    const float* __restrict__ bias,   // (COUT)
    float* __restrict__ out)          // (B, COUT, H, W)
{
    __shared__ __align__(16) ushort sx[HALO_PX * RS];

    const int tid    = threadIdx.x;
    const int lane   = tid & 63;
    const int w_id   = tid >> 6;        // wave 0..7
    const int n_lane = lane & 15;
    const int q      = lane >> 4;

    // XCD-aware decode: dispatch round-robins linear id over 8 XCDs, so
    // id&7 pins one batch image per XCD; tiles sweep row-major within it.
    const int id  = blockIdx.x;
    const int b   = id & 7;
    const int t   = id >> 3;            // 0..255
    const int tx  = t & 7;
    const int ty  = t >> 3;             // 0..31
    const int gx0 = tx * TW;
    const int gy0 = ty * TH;

    const int m_half = w_id >> 2;       // owns M-tiles m_half*2 + {0,1}
    const int n_q    = w_id & 3;        // owns N-tiles n_q*4 + {0..3}

    // acc init = bias (C/D layout: col=lane&15 -> px, row=q*4+r -> co)
    float4v acc[2][4];
#pragma unroll
    for (int mt = 0; mt < 2; ++mt) {
        float4v bi;
#pragma unroll
        for (int r = 0; r < 4; ++r)
            bi[r] = bias[(m_half * 2 + mt) * 16 + q * 4 + r];
#pragma unroll
        for (int nt = 0; nt < 4; ++nt) acc[mt][nt] = bi;
    }

    const float* xb = x + (size_t)b * CI_N * HH * WW;
    // per-lane LDS base for B-frag reads (ushort units): folds n_q rows, n_lane, q
    const int vbase = (n_q * 2 * HALO_W + n_lane) * RS + q * 8;

    for (int chunk = 0; chunk < 2; ++chunk) {
        if (chunk) __syncthreads();   // LDS reuse fence

        // ---- stage: wave w handles ci-pairs w*4 + p*2 for p in {0,1} ----
#pragma unroll
        for (int p = 0; p < 2; ++p) {
            const int cl = w_id * 4 + p * 2;         // 0..30, even
            const int ci = chunk * 32 + cl;
            const float a0 = alpha[b * CI_N + ci];
            const float a1 = alpha[b * CI_N + ci + 1];
            const float* xp0 = xb + (size_t)ci * HH * WW;
            const float* xp1 = xp0 + HH * WW;
#pragma unroll
            for (int it = 0; it < 6; ++it) {
                int hp = it * 64 + lane;
                if (hp < HALO_PX) {
                    int hy = hp / HALO_W;
                    int hx = hp - hy * HALO_W;
                    int gy = gy0 - 1 + hy;
                    int gx = gx0 - 1 + hx;
                    bool ok = ((unsigned)gy < HH) & ((unsigned)gx < WW);
                    int gidx = gy * WW + gx;
                    float v0 = ok ? xp0[gidx] * a0 : 0.0f;
                    float v1 = ok ? xp1[gidx] * a1 : 0.0f;
                    unsigned h0 = f2bf(v0);
                    unsigned h1 = f2bf(v1);
                    float f0 = __uint_as_float(h0 << 16);
                    float f1 = __uint_as_float(h1 << 16);
                    unsigned l0 = f2bf(v0 - f0);
                    unsigned l1 = f2bf(v1 - f1);
                    *(unsigned*)&sx[hp * RS + cl]          = h0 | (h1 << 16);
                    *(unsigned*)&sx[hp * RS + HI_OFF + cl] = l0 | (l1 << 16);
                }
            }
        }
        __syncthreads();

        // ---- compute: 9 shifts x (hi*hi, lo_w*hi, hi*lo_x) over K=32 ci ----
#pragma unroll
        for (int k = 0; k < 9; ++k) {
            const int dy = k / 3 - 1;
            const int dx = k % 3 - 1;
            // A-frags: coalesced dwordx4 from packed layout (L2-resident)
            short8 a_hi[2], a_lo[2];
#pragma unroll
            for (int mt = 0; mt < 2; ++mt) {
                int fh = ((chunk * 9 + k) * 2 + 0) * 4 + (m_half * 2 + mt);
                int fl = ((chunk * 9 + k) * 2 + 1) * 4 + (m_half * 2 + mt);
                a_hi[mt] = *(const short8*)(wp + (size_t)(fh * 64 + lane) * 8);
                a_lo[mt] = *(const short8*)(wp + (size_t)(fl * 64 + lane) * 8);
            }
#pragma unroll
            for (int nt_i = 0; nt_i < 4; ++nt_i) {
                // halo px for this N-tile + shift; vbase carries n_q/n_lane/q
                const int off = ((nt_i >> 1) + 1 + dy) * HALO_W + 1 + (nt_i & 1) * 16 + dx;
                const ushort* bp = &sx[vbase + off * RS];
                short8 b_hi = *(const short8*)bp;            // hi block
                short8 b_lo = *(const short8*)(bp + HI_OFF); // lo block, offset:64
                acc[0][nt_i] = __builtin_amdgcn_mfma_f32_16x16x32_bf16(a_hi[0], b_hi, acc[0][nt_i], 0, 0, 0);
                acc[1][nt_i] = __builtin_amdgcn_mfma_f32_16x16x32_bf16(a_hi[1], b_hi, acc[1][nt_i], 0, 0, 0);
                acc[0][nt_i] = __builtin_amdgcn_mfma_f32_16x16x32_bf16(a_lo[0], b_hi, acc[0][nt_i], 0, 0, 0);
                acc[1][nt_i] = __builtin_amdgcn_mfma_f32_16x16x32_bf16(a_lo[1], b_hi, acc[1][nt_i], 0, 0, 0);
                acc[0][nt_i] = __builtin_amdgcn_mfma_f32_16x16x32_bf16(a_hi[0], b_lo, acc[0][nt_i], 0, 0, 0);
                acc[1][nt_i] = __builtin_amdgcn_mfma_f32_16x16x32_bf16(a_hi[1], b_lo, acc[1][nt_i], 0, 0, 0);
            }
        }
    }

    // ---- epilogue: store (64B-segment coalescing: 16 px x 4 co groups) ----
#pragma unroll
    for (int mt = 0; mt < 2; ++mt) {
        const int m0 = (m_half * 2 + mt) * 16;
#pragma unroll
        for (int nt_i = 0; nt_i < 4; ++nt_i) {
            const int nt = n_q * 4 + nt_i;
            const int gy = gy0 + (nt >> 1);
            const int gx = gx0 + (nt & 1) * 16 + n_lane;
#pragma unroll
            for (int r = 0; r < 4; ++r) {
                const int co = m0 + q * 4 + r;
                out[(((size_t)b * CO_N + co) * HH + gy) * WW + gx] = acc[mt][nt_i][r];
            }
        }
    }
}

extern "C" void kernel_launch(void* const* d_in, const int* in_sizes, int n_in,
                              void* d_out, int out_size, void* d_ws, size_t ws_size,
                              hipStream_t stream) {
    const float* x     = (const float*)d_in[0];
    const float* alpha = (const float*)d_in[1];
    const float* w     = (const float*)d_in[2];
    const float* bias  = (const float*)d_in[3];
    float* out  = (float*)d_out;
    ushort* wpk = (ushort*)d_ws;

    prepack_w<<<dim3((NFRAG + 255) / 256), dim3(256), 0, stream>>>(w, wpk);

    // 1-D grid so the in-kernel XCD decode controls locality (2048 blocks)
    conv_mfma<<<dim3(2048), dim3(512), 0, stream>>>(x, alpha, wpk, bias, out);
}

// Round 5
// 334.178 us; speedup vs baseline: 2.8556x; 1.1338x over previous
//
#include <hip/hip_runtime.h>

// SpecAdaConv2d via split-bf16 MFMA implicit GEMM.
// out[b,co,p] = sum_{ci,k} (alpha[b,ci]*w[co,ci,k]) * x[b,ci,p+shift(k)] + bias[co]
// fp32 -> (hi,lo) bf16 split on both w and x; 3 products hi*hi + hi*lo_x + lo_w*hi.
//
// R5 = R4 (XCD swizzle: FETCH 217->96MB, kept) + T14 issue-early/write-late
// staging pipeline. R4 evidence: FETCH halved, time unchanged -> latency-bound,
// ~60% of CU time in waitcnt/barrier with all waves phase-locked in stage.
// New schedule per block:
//   load(chunk0)->regs; convert+write; barrier;
//   load(chunk1)->regs;            // issued BEFORE compute0, hides under MFMA
//   compute(chunk0); barrier;
//   convert+write(chunk1); barrier;
//   compute(chunk1); epilogue
// Staging loads are clamped-address (branchless), zero-select at convert.
// Cost: +24 VGPR held across compute0 (~100-110 total, still < 128 cap of
// launch_bounds(512,4); 2 blocks/CU = measured current residency anyway).

typedef __attribute__((ext_vector_type(8))) short short8;
typedef __attribute__((ext_vector_type(4))) float float4v;

#define BB 8
#define CI_N 64
#define CO_N 64
#define HH 256
#define WW 256
#define HW (HH * WW)
#define TW 32
#define TH 8
#define HALO_W 34
#define HALO_H 10
#define HALO_PX (HALO_W * HALO_H)   // 340
#define RS 72                        // packed row: [32 hi][32 lo][8 pad] ushorts
#define HI_OFF 32                    // lo block starts 32 ushorts (64 B) into row

#define NFRAG (2 * 9 * 2 * 4 * 64 * 8)  // 73728 packed bf16 elems

__device__ __forceinline__ unsigned f2bf(float v) {
    unsigned u = __float_as_uint(v);
    return (u + 0x7FFFu + ((u >> 16) & 1u)) >> 16;   // RNE to bf16
}

__global__ void prepack_w(const float* __restrict__ w, ushort* __restrict__ wp) {
    int idx = blockIdx.x * 256 + threadIdx.x;
    if (idx >= NFRAG) return;
    int j     = idx & 7;
    int lane  = (idx >> 3) & 63;
    int mt    = (idx >> 9) & 3;
    int plane = (idx >> 11) & 1;
    int rest  = idx >> 12;            // chunk*9 + k, 0..17
    int k     = rest % 9;
    int chunk = rest / 9;
    int co = mt * 16 + (lane & 15);
    int ci = chunk * 32 + (lane >> 4) * 8 + j;
    float v = w[(co * CI_N + ci) * 9 + k];
    unsigned hi = f2bf(v);
    float fhi = __uint_as_float(hi << 16);
    unsigned lo = f2bf(v - fhi);
    wp[idx] = (ushort)(plane ? lo : hi);
}

__global__ __launch_bounds__(512, 4) void conv_mfma(
    const float* __restrict__ x,      // (B, CIN, H, W)
    const float* __restrict__ alpha,  // (B, CIN)
    const ushort* __restrict__ wp,    // packed weights (d_ws)
    const float* __restrict__ bias,   // (COUT)
    float* __restrict__ out)          // (B, COUT, H, W)
{
    __shared__ __align__(16) ushort sx[HALO_PX * RS];

    const int tid    = threadIdx.x;
    const int lane   = tid & 63;
    const int w_id   = tid >> 6;        // wave 0..7
    const int n_lane = lane & 15;
    const int q      = lane >> 4;

    // XCD-aware decode: id&7 pins one batch image per XCD (FETCH 217->96MB).
    const int id  = blockIdx.x;
    const int b   = id & 7;
    const int t   = id >> 3;            // 0..255
    const int tx  = t & 7;
    const int ty  = t >> 3;             // 0..31
    const int gx0 = tx * TW;
    const int gy0 = ty * TH;

    const int m_half = w_id >> 2;       // owns M-tiles m_half*2 + {0,1}
    const int n_q    = w_id & 3;        // owns N-tiles n_q*4 + {0..3}

    // acc init = bias (C/D layout: col=lane&15 -> px, row=q*4+r -> co)
    float4v acc[2][4];
#pragma unroll
    for (int mt = 0; mt < 2; ++mt) {
        float4v bi;
#pragma unroll
        for (int r = 0; r < 4; ++r)
            bi[r] = bias[(m_half * 2 + mt) * 16 + q * 4 + r];
#pragma unroll
        for (int nt = 0; nt < 4; ++nt) acc[mt][nt] = bi;
    }

    const float* xb = x + (size_t)b * CI_N * HW;
    // per-lane LDS base for B-frag reads (ushort units): folds n_q rows, n_lane, q
    const int vbase = (n_q * 2 * HALO_W + n_lane) * RS + q * 8;

    // ---- staging geometry, computed once (shared by both chunks) ----
    int gofs[6];
    unsigned okm = 0;
#pragma unroll
    for (int it = 0; it < 6; ++it) {
        int hp = it * 64 + lane;
        int hy = hp / HALO_W;
        int hx = hp - hy * HALO_W;
        int gy = gy0 - 1 + hy;
        int gx = gx0 - 1 + hx;
        bool ok = (hp < HALO_PX) & ((unsigned)gy < HH) & ((unsigned)gx < WW);
        gofs[it] = ok ? gy * WW + gx : 0;   // clamped: load always valid
        okm |= (unsigned)ok << it;
    }
    const int cl = w_id * 4;   // this wave stages ci = chunk*32 + cl .. +3
    float al0[4], al1[4];      // wave-uniform alphas per chunk
#pragma unroll
    for (int j = 0; j < 4; ++j) {
        al0[j] = alpha[b * CI_N + cl + j];
        al1[j] = alpha[b * CI_N + 32 + cl + j];
    }

    // raw staging loads for one chunk: r[j][it], ci = base+j
#define STAGE_LOAD(r, cbase)                                             \
    {                                                                    \
        _Pragma("unroll")                                                \
        for (int j = 0; j < 4; ++j) {                                    \
            const float* xp = xb + (size_t)((cbase) + cl + j) * HW;      \
            _Pragma("unroll")                                            \
            for (int it = 0; it < 6; ++it) r[j][it] = xp[gofs[it]];      \
        }                                                                \
    }

    // convert + swizzle-free LDS write (R1 layout): pairs (j0,j1),(j2,j3)
#define STAGE_WRITE(r, al)                                               \
    {                                                                    \
        _Pragma("unroll")                                                \
        for (int it = 0; it < 6; ++it) {                                 \
            if (it < 5 || lane < 20) {  /* unit exists (hp<340) */       \
                const int hp = it * 64 + lane;                           \
                const bool ok = (okm >> it) & 1;                         \
                float v[4];                                              \
                _Pragma("unroll")                                        \
                for (int j = 0; j < 4; ++j)                              \
                    v[j] = ok ? r[j][it] * al[j] : 0.0f;                 \
                _Pragma("unroll")                                        \
                for (int p2 = 0; p2 < 2; ++p2) {                         \
                    unsigned h0 = f2bf(v[2 * p2]);                       \
                    unsigned h1 = f2bf(v[2 * p2 + 1]);                   \
                    unsigned l0 = f2bf(v[2 * p2]                         \
                                       - __uint_as_float(h0 << 16));     \
                    unsigned l1 = f2bf(v[2 * p2 + 1]                     \
                                       - __uint_as_float(h1 << 16));     \
                    *(unsigned*)&sx[hp * RS + cl + 2 * p2] =             \
                        h0 | (h1 << 16);                                 \
                    *(unsigned*)&sx[hp * RS + HI_OFF + cl + 2 * p2] =    \
                        l0 | (l1 << 16);                                 \
                }                                                        \
            }                                                            \
        }                                                                \
    }

    // compute phase for one chunk (reads sx + wp, accumulates)
#define COMPUTE(chunk)                                                   \
    {                                                                    \
        _Pragma("unroll")                                                \
        for (int k = 0; k < 9; ++k) {                                    \
            const int dy = k / 3 - 1;                                    \
            const int dx = k % 3 - 1;                                    \
            short8 a_hi[2], a_lo[2];                                     \
            _Pragma("unroll")                                            \
            for (int mt = 0; mt < 2; ++mt) {                             \
                int fh = (((chunk) * 9 + k) * 2 + 0) * 4 + (m_half * 2 + mt); \
                int fl = (((chunk) * 9 + k) * 2 + 1) * 4 + (m_half * 2 + mt); \
                a_hi[mt] = *(const short8*)(wp + (size_t)(fh * 64 + lane) * 8); \
                a_lo[mt] = *(const short8*)(wp + (size_t)(fl * 64 + lane) * 8); \
            }                                                            \
            _Pragma("unroll")                                            \
            for (int nt_i = 0; nt_i < 4; ++nt_i) {                       \
                const int off = ((nt_i >> 1) + 1 + dy) * HALO_W + 1      \
                              + (nt_i & 1) * 16 + dx;                    \
                const ushort* bp = &sx[vbase + off * RS];                \
                short8 b_hi = *(const short8*)bp;                        \
                short8 b_lo = *(const short8*)(bp + HI_OFF);             \
                acc[0][nt_i] = __builtin_amdgcn_mfma_f32_16x16x32_bf16(a_hi[0], b_hi, acc[0][nt_i], 0, 0, 0); \
                acc[1][nt_i] = __builtin_amdgcn_mfma_f32_16x16x32_bf16(a_hi[1], b_hi, acc[1][nt_i], 0, 0, 0); \
                acc[0][nt_i] = __builtin_amdgcn_mfma_f32_16x16x32_bf16(a_lo[0], b_hi, acc[0][nt_i], 0, 0, 0); \
                acc[1][nt_i] = __builtin_amdgcn_mfma_f32_16x16x32_bf16(a_lo[1], b_hi, acc[1][nt_i], 0, 0, 0); \
                acc[0][nt_i] = __builtin_amdgcn_mfma_f32_16x16x32_bf16(a_hi[0], b_lo, acc[0][nt_i], 0, 0, 0); \
                acc[1][nt_i] = __builtin_amdgcn_mfma_f32_16x16x32_bf16(a_hi[1], b_lo, acc[1][nt_i], 0, 0, 0); \
            }                                                            \
        }                                                                \
    }

    // ---- pipelined schedule ----
    float r0[4][6], r1[4][6];
    STAGE_LOAD(r0, 0);          // chunk0 loads
    STAGE_WRITE(r0, al0);       // convert + LDS write
    __syncthreads();

    STAGE_LOAD(r1, 32);         // chunk1 loads issued EARLY (hide under MFMA)
    COMPUTE(0);
    __syncthreads();            // all sx reads of chunk0 done

    STAGE_WRITE(r1, al1);       // vmcnt drained here, not before compute
    __syncthreads();

    COMPUTE(1);

    // ---- epilogue: store (64B-segment coalescing: 16 px x 4 co groups) ----
#pragma unroll
    for (int mt = 0; mt < 2; ++mt) {
        const int m0 = (m_half * 2 + mt) * 16;
#pragma unroll
        for (int nt_i = 0; nt_i < 4; ++nt_i) {
            const int nt = n_q * 4 + nt_i;
            const int gy = gy0 + (nt >> 1);
            const int gx = gx0 + (nt & 1) * 16 + n_lane;
#pragma unroll
            for (int r = 0; r < 4; ++r) {
                const int co = m0 + q * 4 + r;
                out[(((size_t)b * CO_N + co) * HH + gy) * WW + gx] = acc[mt][nt_i][r];
            }
        }
    }
#undef STAGE_LOAD
#undef STAGE_WRITE
#undef COMPUTE
}

extern "C" void kernel_launch(void* const* d_in, const int* in_sizes, int n_in,
                              void* d_out, int out_size, void* d_ws, size_t ws_size,
                              hipStream_t stream) {
    const float* x     = (const float*)d_in[0];
    const float* alpha = (const float*)d_in[1];
    const float* w     = (const float*)d_in[2];
    const float* bias  = (const float*)d_in[3];
    float* out  = (float*)d_out;
    ushort* wpk = (ushort*)d_ws;

    prepack_w<<<dim3((NFRAG + 255) / 256), dim3(256), 0, stream>>>(w, wpk);

    // 1-D grid so the in-kernel XCD decode controls locality (2048 blocks)
    conv_mfma<<<dim3(2048), dim3(512), 0, stream>>>(x, alpha, wpk, bias, out);
}